// Round 11
// baseline (51.692 us; speedup 1.0000x reference)
//
#include <hip/hip_runtime.h>
#include <cmath>

// Bokeh render, gather form:
// out[b,c,y,x] = sum_{dy,dx in [-4,4]} w * img[b,c,y-dy,x-dx] / sum w
// w = sigmoid(8*(r_src - dist)) / max(pi*r_src^2,1);  r = |defocus| in [0,4).
// Window mask dropped (outside-window w <= sigma(-8): output shift <2e-5).
// OOB sources exact via Iv=0.
//
// R11 DIAGNOSTIC: R10 (19.4us, best) runs 4 main-loop passes (pass0 -> out,
// 1-3 -> ws). Purpose: (a) kernel rises above the 38us profiler cutoff ->
// first counters for this structure; (b) pass-marginal M = (dur-19.4)/3
// separates main-loop cost from staging+overhead. Structure is IDENTICAL
// to R10 otherwise (2 dy-groups, bf16 3-array LDS, unroll-1 row loop,
// sFd broadcasts). Pre-committed R12 branch: conflicts>=1e7 -> swizzle;
// VALU>65% -> unpack/rcp cuts; both low -> deeper occupancy.

#define HH 512
#define WW 512
#define NB 2
#define TW 64                     // tile width (16 quads, zero waste)
#define TH 16                     // tile height
#define HALO 4
#define SROWS (TH + 2 * HALO)     // 24
#define LW 72                     // 4 + 64 + 4 = exactly 72 dwords/row

__device__ __forceinline__ unsigned rtne_hi(float v) {
  unsigned u = __float_as_uint(v);
  u = u + 0x7FFFu + ((u >> 16) & 1u);
  return u & 0xFFFF0000u;
}

__global__ __launch_bounds__(512, 4) void bokeh_gather(
    const float* __restrict__ img,
    const float* __restrict__ def,
    float* __restrict__ out,
    float* __restrict__ out2)
{
  __shared__ __align__(16) unsigned sX[SROWS][LW];  // G(hi) | Iv(lo)   bf16
  __shared__ __align__(16) unsigned sY[SROWS][LW];  // c0(hi) | c1(lo)  bf16
  __shared__ __align__(16) unsigned sZ[SROWS][LW];  // c2 truncated f32
  __shared__ float sFd[9][12];                      // exp(8*dist(dy,dx))
  __shared__ __align__(16) float pbuf[256][20];     // group-1 partials

  const int tid = threadIdx.x;
  const int s   = tid >> 8;      // dy-group: 0 -> dy 0..4, 1 -> dy 5..8
  const int t   = tid & 255;
  const int tx  = t & 15;        // 16 lanes * 4 px = 64 cols
  const int ty  = t >> 4;        // 16 rows
  const int bx = blockIdx.x * TW;
  const int by = blockIdx.y * TH;
  const int b  = blockIdx.z;

  if (tid < 81) {
    int dyi = tid / 9, dxi = tid - dyi * 9;
    int dyo = dyi - 4, dxo = dxi - 4;
    float d2 = (float)(dyo * dyo + dxo * dxo);
    sFd[dyi][dxi] = __expf(8.0f * sqrtf(d2));
  }

  const float* dpt = def + b * (HH * WW);
  const float* ipt = img + b * (3 * HH * WW);

  for (int idx = tid; idx < SROWS * LW; idx += 512) {
    int ly = idx / LW;
    int lx = idx - ly * LW;
    int sy = by - HALO + ly;
    int sx = bx - HALO + lx;
    unsigned X = 0u, Y = 0u, Z = 0u;
    if ((unsigned)sy < (unsigned)HH && (unsigned)sx < (unsigned)WW) {
      int o = sy * WW + sx;
      float r = fabsf(dpt[o]);
      float G  = __expf(-8.0f * r);
      float iv = __builtin_amdgcn_rcpf(fmaxf(3.14159265358979f * r * r, 1.0f));
      X = rtne_hi(G) | (rtne_hi(iv) >> 16);
      Y = rtne_hi(ipt[o]) | (rtne_hi(ipt[o + HH * WW]) >> 16);
      Z = __float_as_uint(ipt[o + 2 * HH * WW]) & 0xFFFF0000u;
    }
    sX[ly][lx] = X;
    sY[ly][lx] = Y;
    sZ[ly][lx] = Z;
  }
  __syncthreads();

  const int col0 = 4 * tx;       // window start col (16B aligned)
  const int dy0 = s ? 5 : 0;
  const int dy1 = s ? 9 : 5;

  #pragma unroll 1
  for (int pass = 0; pass < 4; ++pass) {
    asm volatile("" ::: "memory");   // no CSE across passes (R3/R4-proven)

    float wsum[4] = {0.f, 0.f, 0.f, 0.f};
    float ac0[4]  = {0.f, 0.f, 0.f, 0.f};
    float ac1[4]  = {0.f, 0.f, 0.f, 0.f};
    float ac2[4]  = {0.f, 0.f, 0.f, 0.f};

    #pragma unroll 1
    for (int dy = dy0; dy < dy1; ++dy) {
      const int sr = ty + dy;
      float fdr[9];
      #pragma unroll
      for (int x = 0; x < 9; ++x) fdr[x] = sFd[dy][x];

      unsigned Xv[12], Yv[12], Zv[12];
      #pragma unroll
      for (int q = 0; q < 3; ++q) {
        *(uint4*)&Xv[4 * q] = *(const uint4*)(&sX[sr][col0] + 4 * q);
        *(uint4*)&Yv[4 * q] = *(const uint4*)(&sY[sr][col0] + 4 * q);
        *(uint4*)&Zv[4 * q] = *(const uint4*)(&sZ[sr][col0] + 4 * q);
      }
      float Gv[12], Iv[12], C0[12], C1[12];
      #pragma unroll
      for (int j = 0; j < 12; ++j) {
        Gv[j] = __uint_as_float(Xv[j] & 0xFFFF0000u);
        Iv[j] = __uint_as_float(Xv[j] << 16);
        C0[j] = __uint_as_float(Yv[j] & 0xFFFF0000u);
        C1[j] = __uint_as_float(Yv[j] << 16);
      }

      #pragma unroll
      for (int k = 0; k < 4; ++k) {
        #pragma unroll
        for (int j = k; j < k + 9; ++j) {
          const int xi = j - k;                      // compile-time
          float tden = fmaf(Gv[j], fdr[xi], 1.0f);   // 1 + e^{-8r} e^{8d}
          float w = __builtin_amdgcn_rcpf(tden) * Iv[j];
          wsum[k] += w;
          ac0[k] = fmaf(w, C0[j], ac0[k]);
          ac1[k] = fmaf(w, C1[j], ac1[k]);
          ac2[k] = fmaf(w, __uint_as_float(Zv[j]), ac2[k]);
        }
      }
    }

    // Combine dy-halves: group 1 publishes, group 0 reduces + stores.
    if (s == 1) {
      float4 v0 = {wsum[0], wsum[1], wsum[2], wsum[3]};
      float4 v1 = {ac0[0], ac0[1], ac0[2], ac0[3]};
      float4 v2 = {ac1[0], ac1[1], ac1[2], ac1[3]};
      float4 v3 = {ac2[0], ac2[1], ac2[2], ac2[3]};
      *(float4*)&pbuf[t][0]  = v0;
      *(float4*)&pbuf[t][4]  = v1;
      *(float4*)&pbuf[t][8]  = v2;
      *(float4*)&pbuf[t][12] = v3;
    }
    __syncthreads();
    if (s == 0) {
      float4 v0 = *(const float4*)&pbuf[t][0];
      float4 v1 = *(const float4*)&pbuf[t][4];
      float4 v2 = *(const float4*)&pbuf[t][8];
      float4 v3 = *(const float4*)&pbuf[t][12];
      wsum[0] += v0.x; wsum[1] += v0.y; wsum[2] += v0.z; wsum[3] += v0.w;
      ac0[0] += v1.x; ac0[1] += v1.y; ac0[2] += v1.z; ac0[3] += v1.w;
      ac1[0] += v2.x; ac1[1] += v2.y; ac1[2] += v2.z; ac1[3] += v2.w;
      ac2[0] += v3.x; ac2[1] += v3.y; ac2[2] += v3.z; ac2[3] += v3.w;

      const int oy = by + ty;
      const int ox = bx + col0;
      float rw[4];
      #pragma unroll
      for (int k = 0; k < 4; ++k) rw[k] = __builtin_amdgcn_rcpf(wsum[k]);

      float* dst = pass ? out2 : out;
      float* op0 = dst + ((b * 3 + 0) * HH + oy) * WW + ox;
      float* op1 = dst + ((b * 3 + 1) * HH + oy) * WW + ox;
      float* op2 = dst + ((b * 3 + 2) * HH + oy) * WW + ox;
      float4 o0, o1, o2;
      o0.x = ac0[0] * rw[0]; o0.y = ac0[1] * rw[1]; o0.z = ac0[2] * rw[2]; o0.w = ac0[3] * rw[3];
      o1.x = ac1[0] * rw[0]; o1.y = ac1[1] * rw[1]; o1.z = ac1[2] * rw[2]; o1.w = ac1[3] * rw[3];
      o2.x = ac2[0] * rw[0]; o2.y = ac2[1] * rw[1]; o2.z = ac2[2] * rw[2]; o2.w = ac2[3] * rw[3];
      *(float4*)op0 = o0;
      *(float4*)op1 = o1;
      *(float4*)op2 = o2;
    }
    __syncthreads();   // pbuf safe to rewrite next pass
  }
}

extern "C" void kernel_launch(void* const* d_in, const int* in_sizes, int n_in,
                              void* d_out, int out_size, void* d_ws, size_t ws_size,
                              hipStream_t stream) {
  const float* img = (const float*)d_in[0];   // (2,3,512,512) f32
  const float* def = (const float*)d_in[1];   // (2,1,512,512) f32
  float* out = (float*)d_out;                 // (2,3,512,512) f32
  float* out2 = (ws_size >= (size_t)out_size * sizeof(float))
                    ? (float*)d_ws : out;

  dim3 grid(WW / TW, HH / TH, NB);            // 8 x 32 x 2 = 512 blocks = 2/CU
  dim3 block(512);
  hipLaunchKernelGGL(bokeh_gather, grid, block, 0, stream, img, def, out, out2);
}